// Round 15
// baseline (134.216 us; speedup 1.0000x reference)
//
#include <hip/hip_runtime.h>

typedef float f32x4  __attribute__((ext_vector_type(4)));
typedef float f32x16 __attribute__((ext_vector_type(16)));
typedef __bf16 bf16x8 __attribute__((ext_vector_type(8)));

#define SPAT 65536   // t*h*w
#define CH   128
#define NE   8

// LDS: params only (no weight staging, no main-loop barriers)
#define B1_OFF   0       // 4096 : b1 f32[8][128]
#define B2T_OFF  4096    // 4096 : b2^T bf16[128][16] (e 8..15 zero)
#define AL_OFF   8192    // 32   : alpha f32[8]
#define LDS_BYTES 8224

#define SB() __builtin_amdgcn_sched_barrier(0)

static __device__ __forceinline__ unsigned short bf(float f) {
    __bf16 h = (__bf16)f; return __builtin_bit_cast(unsigned short, h);
}
static __device__ __forceinline__ unsigned pk2(float a, float b) {
    return (unsigned)bf(a) | ((unsigned)bf(b) << 16);
}

// Pre-convert W1/W2 fp32 -> bf16 LANE-LINEAR images (both read straight from
// global/L1/L2 by the main kernel; no LDS weights).
// Logical access (R7/R8-verified math): instruction (lineHi, lineLo) reads
// row r = lineLo*32 + ltok, granule p = 2*lineHi + hi, i.e. one contiguous
// 1KB line per instruction: byte = (lineHi*4 + lineLo)*1024 + hi*512 + ltok*16.
// Store granule p of row r at ((p>>1)*4 + (r>>5))<<10 | (p&1)<<9 | (r&31)*16.
// W1 rows PERMUTED (image row r holds real W1 row P(r)):
//   n = 4*(r>>5) + ((r>>3)&3); P(r) = (n>>1)*16 + ((r>>2)&1)*8 + (n&1)*4 + (r&3)
// so GEMM1's D-fragment == GEMM2's A-fragment (h1 stays in registers).
__global__ void conv_w(const float* __restrict__ W1, const float* __restrict__ W2,
                       unsigned char* __restrict__ wimg) {
    const int gid = blockIdx.x * 256 + threadIdx.x;   // 32768 granules
    const int mat = gid >> 14;
    const int e   = (gid >> 11) & 7;
    const int r   = (gid >> 4) & 127;
    const int p   = gid & 15;
    int src_row = r;
    if (mat == 0) {
        const int n = 4 * (r >> 5) + ((r >> 3) & 3);
        src_row = (n >> 1) * 16 + ((r >> 2) & 1) * 8 + (n & 1) * 4 + (r & 3);
    }
    const float* s = (mat ? W2 : W1) + (e * 16384 + src_row * 128 + p * 8);
    uint4 pk;
    pk.x = pk2(s[0], s[1]); pk.y = pk2(s[2], s[3]);
    pk.z = pk2(s[4], s[5]); pk.w = pk2(s[6], s[7]);
    *(uint4*)(wimg + mat * 262144 + e * 32768
              + ((((p >> 1) * 4 + (r >> 5)) << 10) + ((p & 1) << 9) + (r & 31) * 16)) = pk;
}

// load the 8 a1 fragments of group g (one 1KB line each, contiguous)
static __device__ __forceinline__ void ld_a1g(uint4* buf, const unsigned char* __restrict__ base,
                                              int g, int wlane) {
    #pragma unroll
    for (int kc = 0; kc < 8; ++kc)
        buf[kc] = *(const uint4*)(base + ((kc * 4 + g) << 10) + wlane);
}

// One (expert e, group g) step. Issue order matters (vmcnt pipeline):
//   (1) wfb loads for this g   -> newest 8 when GEMM2 waits: vmcnt(8) keeps nxt in flight
//   (2) a1 prefetch for it+1   -> survives across the whole body
//   (3) h chain on cur (waits cur = loads issued one body ago, fully covered)
//   (4) PReLU -> pa2 ; (5) GEMM2 (waits wfb only)
static __device__ __forceinline__ void body(
        int it, uint4* cur, uint4* nxt,
        const unsigned char* __restrict__ wimg, const unsigned char* smem,
        int wlane, int hi, int i0, int i1, float q0, float q1,
        const uint4* xb, f32x16* acc)
{
    const int e = it >> 2, g = it & 3;
    const unsigned char* W2g = wimg + 262144 + e * 32768;

    uint4 wfb[8];
    #pragma unroll
    for (int dk = 0; dk < 2; ++dk)
        #pragma unroll
        for (int n2 = 0; n2 < 4; ++n2)
            wfb[dk * 4 + n2] = *(const uint4*)(W2g + (((2 * g + dk) * 4 + n2) << 10) + wlane);
    SB();
    if (it < 31) {
        const int en = (it + 1) >> 2, gn = (it + 1) & 3;
        ld_a1g(nxt, wimg + en * 32768, gn, wlane);
    }
    SB();

    f32x16 h0 = {}, h1 = {};
    #pragma unroll
    for (int kc = 0; kc < 4; ++kc) {
        h0 = __builtin_amdgcn_mfma_f32_32x32x16_bf16(
                __builtin_bit_cast(bf16x8, cur[2 * kc]),
                __builtin_bit_cast(bf16x8, xb[2 * kc]), h0, 0, 0, 0);
        h1 = __builtin_amdgcn_mfma_f32_32x32x16_bf16(
                __builtin_bit_cast(bf16x8, cur[2 * kc + 1]),
                __builtin_bit_cast(bf16x8, xb[2 * kc + 1]), h1, 0, 0, 0);
    }
    const float alph = ((const float*)(smem + AL_OFF))[e];
    const float ce = (i0 == e) ? q0 : ((i1 == e) ? q1 : 0.f);
    uint4 pa2[2];
    #pragma unroll
    for (int q = 0; q < 4; ++q) {
        const int n = 4 * g + q, kt2 = n >> 1, half = n & 1;
        const int obase = kt2 * 16 + hi * 8 + half * 4;
        const f32x4 b1v = *(const f32x4*)(smem + B1_OFF + e * 512 + obase * 4);
        float hv[4];
        #pragma unroll
        for (int i = 0; i < 4; ++i) {
            float z = h0[q * 4 + i] + h1[q * 4 + i] + b1v[i];
            z = (z > 0.f) ? z : alph * z;
            hv[i] = z * ce;
        }
        ((unsigned*)&pa2[q >> 1])[half * 2]     = pk2(hv[0], hv[1]);
        ((unsigned*)&pa2[q >> 1])[half * 2 + 1] = pk2(hv[2], hv[3]);
    }
    SB();
    #pragma unroll
    for (int dk = 0; dk < 2; ++dk)
        #pragma unroll
        for (int n2 = 0; n2 < 4; ++n2)
            acc[n2] = __builtin_amdgcn_mfma_f32_32x32x16_bf16(
                    __builtin_bit_cast(bf16x8, pa2[dk]),
                    __builtin_bit_cast(bf16x8, wfb[dk * 4 + n2]), acc[n2], 0, 0, 0);
}

// (2,2) pin -> 256-reg budget. One barrier total; waves free-run through the
// expert loop (acc in-register, tokens wave-owned, weights from global/L1/L2)
// so the two resident waves per SIMD drift out of phase and cover each other.
__global__ __launch_bounds__(512) __attribute__((amdgpu_waves_per_eu(2, 2)))
void moe_main(const float* __restrict__ x,  const float* __restrict__ gw,
              const float* __restrict__ gb, const float* __restrict__ b1,
              const float* __restrict__ alpha, const float* __restrict__ b2,
              const unsigned char* __restrict__ wimg, float* __restrict__ out)
{
    __shared__ __align__(16) unsigned char smem[LDS_BYTES];
    const int t = threadIdx.x, lane = t & 63, w = t >> 6, blk = blockIdx.x;
    const int ltok = lane & 31, hi = lane >> 5;
    const size_t xbase = (size_t)(blk >> 8) * (size_t)(CH * SPAT) + (size_t)((blk & 255) << 8);
    const int m = w * 32 + ltok;             // this lane's block-local token
    const int wlane = (hi << 9) + ltok * 16; // per-lane byte offset in weight lines

    // first a1 batch (e=0,g=0) in flight under the whole prologue
    uint4 bufA[8], bufB[8];
    ld_a1g(bufA, wimg, 0, wlane);

    // stage small params
    if (t < 256) ((f32x4*)(smem + B1_OFF))[t] = ((const f32x4*)b1)[t];
    if (t < 128) {
        uint4 pkv, z4 = {0u, 0u, 0u, 0u};
        pkv.x = pk2(b2[0 * 128 + t], b2[1 * 128 + t]);
        pkv.y = pk2(b2[2 * 128 + t], b2[3 * 128 + t]);
        pkv.z = pk2(b2[4 * 128 + t], b2[5 * 128 + t]);
        pkv.w = pk2(b2[6 * 128 + t], b2[7 * 128 + t]);
        *(uint4*)(smem + B2T_OFF + t * 32)      = pkv;
        *(uint4*)(smem + B2T_OFF + t * 32 + 16) = z4;
    } else if (t >= 128 && t < 136) {
        ((float*)(smem + AL_OFF))[t - 128] = alpha[t - 128];
    }

    // ---- per-kc: load x(8ch), fp32 gating partials (gw from global/L2), pack xb ----
    f32x4 plo = {0.f,0.f,0.f,0.f}, phi = {0.f,0.f,0.f,0.f};
    uint4 xb[8];
    #pragma unroll
    for (int kc = 0; kc < 8; ++kc) {
        const int c0 = kc * 16 + hi * 8;
        float v8[8];
        #pragma unroll
        for (int j = 0; j < 8; ++j) v8[j] = x[xbase + (size_t)(c0 + j) * SPAT + m];
        #pragma unroll
        for (int j = 0; j < 8; ++j) {
            const f32x4 g0 = *(const f32x4*)(gw + (c0 + j) * NE);
            const f32x4 g1 = *(const f32x4*)(gw + (c0 + j) * NE + 4);
            plo += v8[j] * g0; phi += v8[j] * g1;
        }
        xb[kc].x = pk2(v8[0], v8[1]); xb[kc].y = pk2(v8[2], v8[3]);
        xb[kc].z = pk2(v8[4], v8[5]); xb[kc].w = pk2(v8[6], v8[7]);
    }
    #pragma unroll
    for (int i2 = 0; i2 < 4; ++i2) {
        plo[i2] += __shfl_xor(plo[i2], 32, 64);
        phi[i2] += __shfl_xor(phi[i2], 32, 64);
    }
    int i0, i1; float q0, q1; uint4 cbw;
    {
        float lg[8];
        #pragma unroll
        for (int e2 = 0; e2 < 4; ++e2) { lg[e2] = plo[e2] + gb[e2]; lg[4 + e2] = phi[e2] + gb[4 + e2]; }
        i0 = 0; float v0 = lg[0];
        #pragma unroll
        for (int e2 = 1; e2 < 8; ++e2) if (lg[e2] > v0) { v0 = lg[e2]; i0 = e2; }
        i1 = -1; float v1 = -3.4e38f;
        #pragma unroll
        for (int e2 = 0; e2 < 8; ++e2) if (e2 != i0 && lg[e2] > v1) { v1 = lg[e2]; i1 = e2; }
        const float d = expf(v1 - v0);
        q0 = 1.f / (1.f + d);
        q1 = d   / (1.f + d);
        float cb[8];
        #pragma unroll
        for (int e2 = 0; e2 < 8; ++e2) cb[e2] = (e2 == i0) ? q0 : ((e2 == i1) ? q1 : 0.f);
        cbw.x = pk2(cb[0], cb[1]); cbw.y = pk2(cb[2], cb[3]);
        cbw.z = pk2(cb[4], cb[5]); cbw.w = pk2(cb[6], cb[7]);
    }
    __syncthreads();   // S1 (the only barrier): params visible

    f32x16 acc[4] = {};   // acc[n2]: D[tok 32][p = n2*32 + ltok]

    // 32 (expert,group) steps, rolling named buffers (bounded liveness, R12)
    #pragma unroll 1
    for (int itp = 0; itp < 16; ++itp) {
        body(2 * itp,     bufA, bufB, wimg, smem, wlane, hi, i0, i1, q0, q1, xb, acc);
        body(2 * itp + 1, bufB, bufA, wimg, smem, wlane, hi, i0, i1, q0, q1, xb, acc);
    }

    // ---- bias-combine as one K=16 MFMA per p-group: acc += combine . b2 ----
    {
        const uint4 z4 = {0u, 0u, 0u, 0u};
        const uint4 aop = hi ? z4 : cbw;
        #pragma unroll
        for (int n2 = 0; n2 < 4; ++n2) {
            const uint4 bop = *(const uint4*)(smem + B2T_OFF + (n2 * 32 + ltok) * 32 + hi * 16);
            acc[n2] = __builtin_amdgcn_mfma_f32_32x32x16_bf16(
                    __builtin_bit_cast(bf16x8, aop),
                    __builtin_bit_cast(bf16x8, bop), acc[n2], 0, 0, 0);
        }
    }

    // ---- epilogue: residual + f32x4 stores (D rows: tok = w*32 + 8q + 4hi + i) ----
    #pragma unroll
    for (int n2 = 0; n2 < 4; ++n2) {
        const int p = n2 * 32 + ltok;
        #pragma unroll
        for (int q = 0; q < 4; ++q) {
            const int tok0 = w * 32 + q * 8 + hi * 4;
            const size_t a = xbase + (size_t)p * SPAT + tok0;
            const f32x4 xv = *(const f32x4*)(x + a);
            f32x4 r;
            #pragma unroll
            for (int i = 0; i < 4; ++i) r[i] = acc[n2][q * 4 + i] + xv[i];
            *(f32x4*)(out + a) = r;
        }
    }
}

extern "C" void kernel_launch(void* const* d_in, const int* in_sizes, int n_in,
                              void* d_out, int out_size, void* d_ws, size_t ws_size,
                              hipStream_t stream) {
    const float* x  = (const float*)d_in[0];
    const float* gw = (const float*)d_in[1];
    const float* gb = (const float*)d_in[2];
    const float* W1 = (const float*)d_in[3];
    const float* b1 = (const float*)d_in[4];
    const float* al = (const float*)d_in[5];
    const float* W2 = (const float*)d_in[6];
    const float* b2 = (const float*)d_in[7];
    (void)in_sizes; (void)n_in; (void)out_size; (void)ws_size;
    unsigned char* wimg = (unsigned char*)d_ws;   // needs 512 KiB
    float* out = (float*)d_out;

    conv_w<<<dim3(128), dim3(256), 0, stream>>>(W1, W2, wimg);
    moe_main<<<dim3(512), dim3(512), 0, stream>>>(x, gw, gb, b1, al, b2, wimg, out);
}